// Round 7
// baseline (777.608 us; speedup 1.0000x reference)
//
#include <hip/hip_runtime.h>
#include <stdint.h>

// ---------------------------------------------------------------------------
// LayerNormDenseGeneral: y = LN(x)*scale+bias; z = y @ W.  Outputs (z, y).
// Shapes: x[S,B,H]=[2048,4,2048] fp32, W[H,F]=[2048,8192] fp32.
// Round 9: GEMM with COUNTED lgkm pipeline (the piece all prior rounds
// lacked). r6 post-mortem: all pipes serial (ds 1150 + mfma 1030 + valu 320
// + sync = 2810 cyc/tile); r5's reg-dbuf failed because distance-3 staging
// forces lgkmcnt(0) at every barrier (WAR on buf[t&3]). Fix: distance-2 on
// a 4-buf ring -> body t+1 overwrites buf[(t-1)&3], so reads(t-1) need only
// drain by barrier t: counted s_waitcnt lgkmcnt(12) (waits prev tile's 12
// reads, current tile's 12 float). Body t: {stage t+2 (4 gloads);
// 12 ds_reads(t)->set t&1; lgkmcnt(12); MFMA(t-1) on set (t-1)&1 [register-
// only, overlaps the in-flight reads]; vmcnt(4); barrier}. vmcnt never <4,
// lgkm never drained. 16x16x32 MFMA (0-conflict pattern, r3-r5 verified;
// 32x32 pattern re-conflicted 2.5e7 -> reverted). VALU diet: per-lane
// offsets hoisted, scalar tile advance, ds imm offsets. nt C-store reverted
// (cost +31MB write). LN/transpose keep r6's nt loads (net -35us).
// ws layout: [0, M*K*2) = A bf16 ; [M*K*2, M*K*2 + F*K*2) = Bt bf16. 64 MiB.
// ---------------------------------------------------------------------------

typedef __attribute__((ext_vector_type(8))) short short8;   // 8 x bf16 bits
typedef __attribute__((ext_vector_type(4))) float floatx4;  // MFMA acc
typedef __attribute__((ext_vector_type(4))) float f32x4;

__device__ __forceinline__ unsigned short f2bf(float f) {
    unsigned u = __builtin_bit_cast(unsigned, f);
    u += 0x7fffu + ((u >> 16) & 1u);   // round-to-nearest-even
    return (unsigned short)(u >> 16);
}

// ---------------- LayerNorm: one block per row, H=2048 ---------------------
__global__ __launch_bounds__(256) void ln_kernel(
    const float* __restrict__ x, const float* __restrict__ scale,
    const float* __restrict__ bias, float* __restrict__ y,
    unsigned short* __restrict__ ybf, int H)
{
    const int row = blockIdx.x;
    const float* xr = x + (size_t)row * H;
    const int tid = threadIdx.x;

    f32x4 v0 = __builtin_nontemporal_load((const f32x4*)xr + tid);
    f32x4 v1 = __builtin_nontemporal_load((const f32x4*)xr + tid + 256);

    float s  = v0[0] + v0[1] + v0[2] + v0[3] + v1[0] + v1[1] + v1[2] + v1[3];
    float ss = v0[0]*v0[0] + v0[1]*v0[1] + v0[2]*v0[2] + v0[3]*v0[3]
             + v1[0]*v1[0] + v1[1]*v1[1] + v1[2]*v1[2] + v1[3]*v1[3];

    #pragma unroll
    for (int off = 32; off > 0; off >>= 1) {
        s  += __shfl_down(s,  off, 64);
        ss += __shfl_down(ss, off, 64);
    }
    __shared__ float rs[4], rq[4];
    if ((tid & 63) == 0) { rs[tid >> 6] = s; rq[tid >> 6] = ss; }
    __syncthreads();
    float ts = rs[0] + rs[1] + rs[2] + rs[3];
    float tq = rq[0] + rq[1] + rq[2] + rq[3];
    float mean = ts / (float)H;
    float var  = tq / (float)H - mean * mean;
    float rstd = rsqrtf(var + 1e-6f);

    f32x4 sc0 = ((const f32x4*)scale)[tid];
    f32x4 sc1 = ((const f32x4*)scale)[tid + 256];
    f32x4 b0  = ((const f32x4*)bias)[tid];
    f32x4 b1  = ((const f32x4*)bias)[tid + 256];

    f32x4 o0 = (v0 - mean) * rstd * sc0 + b0;
    f32x4 o1 = (v1 - mean) * rstd * sc1 + b1;

    float* yr = y + (size_t)row * H;
    __builtin_nontemporal_store(o0, (f32x4*)yr + tid);
    __builtin_nontemporal_store(o1, (f32x4*)yr + tid + 256);

    unsigned short* br = ybf + (size_t)row * H;
    uint2 p0, p1;
    p0.x = (unsigned)f2bf(o0[0]) | ((unsigned)f2bf(o0[1]) << 16);
    p0.y = (unsigned)f2bf(o0[2]) | ((unsigned)f2bf(o0[3]) << 16);
    p1.x = (unsigned)f2bf(o1[0]) | ((unsigned)f2bf(o1[1]) << 16);
    p1.y = (unsigned)f2bf(o1[2]) | ((unsigned)f2bf(o1[3]) << 16);
    ((uint2*)br)[tid]       = p0;   // cached: re-read by GEMM
    ((uint2*)br)[tid + 256] = p1;
}

// -------- transpose-cast: W[K][F] fp32 -> Bt[F][K] bf16, 64x64 tiles -------
__global__ __launch_bounds__(256) void transpose_cast_kernel(
    const float* __restrict__ W, unsigned short* __restrict__ Bt,
    int K, int F)
{
    __shared__ float tile[64][65];
    const int kBase = blockIdx.y * 64;
    const int fBase = blockIdx.x * 64;
    const int tid = threadIdx.x;

    #pragma unroll
    for (int p = 0; p < 4; ++p) {
        int kl = (tid >> 4) + p * 16;
        int fl = (tid & 15) * 4;
        f32x4 v = __builtin_nontemporal_load(
            (const f32x4*)&W[(size_t)(kBase + kl) * F + fBase + fl]);
        tile[kl][fl]     = v[0];
        tile[kl][fl + 1] = v[1];
        tile[kl][fl + 2] = v[2];
        tile[kl][fl + 3] = v[3];
    }
    __syncthreads();

    #pragma unroll
    for (int p = 0; p < 2; ++p) {
        int fl = (tid >> 3) + p * 32;
        int k8 = (tid & 7) * 8;
        unsigned w[4];
        #pragma unroll
        for (int j = 0; j < 4; ++j) {
            unsigned lo = f2bf(tile[k8 + 2*j][fl]);
            unsigned hi = f2bf(tile[k8 + 2*j + 1][fl]);
            w[j] = lo | (hi << 16);
        }
        uint4 out = make_uint4(w[0], w[1], w[2], w[3]);
        *(uint4*)&Bt[(size_t)(fBase + fl) * K + kBase + k8] = out;  // cached
    }
}

// ---------------- GEMM: C[M][N] = A[M][K] * Bt[N][K]^T (bf16 -> fp32) ------
// 256x256 tile, BK=32, 512 threads = 8 waves (2M x 4N), wave tile 128x64.
// LDS ring: 4 bufs x (A[256][32] @ 0 + B[256][32] @ 8192 shorts) = 128 KiB.
// Swizzle: phys slot s of row r holds chunk s ^ ((r>>1)&3); inverse XOR on
// the global source; fragment reads conflict-free (r3-r5 measured 0).
//
// Pipeline (distance-2, counted waits, reg X/Y frag dbuf):
//   body t (buf u=t&3): STAGE tile t+2 -> buf[(t+2)&3]   (4 gload_lds)
//                       12 ds_read frags(t) -> set (t&1)
//                       s_waitcnt lgkmcnt(12)   [reads(t-1) complete]
//                       MFMA(t-1) on set ((t-1)&1)  [register-only]
//                       s_waitcnt vmcnt(4)      [tile t+1 resident]
//                       s_barrier
// WAR: body t+1 stages into buf[(t+3)&3] = buf[(t-1)&3]; reads(t-1) drained
// by body t's lgkmcnt(12) + barrier. RAW: reads(t) hit buf staged in body
// t-2, retired by body t-1's vmcnt(4) + barrier. Tail dups write dead bufs.
#define GBM 256
#define GBN 256
#define GBK 32

__device__ __forceinline__ void gload16(const unsigned short* src,
                                        unsigned short* dst) {
    __builtin_amdgcn_global_load_lds(
        (const __attribute__((address_space(1))) unsigned int*)src,
        (__attribute__((address_space(3))) unsigned int*)dst, 16, 0, 0);
}

__global__ __launch_bounds__(512, 2) void gemm_bf16_8w(
    const unsigned short* __restrict__ A,   // [M][K] bf16
    const unsigned short* __restrict__ Bt,  // [N][K] bf16
    float* __restrict__ C,                  // [M][N] fp32
    int M, int N, int K)
{
    __shared__ __align__(128) unsigned short lds[4][16384]; // 128 KiB ring

    const int tid   = threadIdx.x;
    const int lane  = tid & 63;
    const int wave  = tid >> 6;     // 0..7
    const int waveM = wave >> 2;    // 0..1
    const int waveN = wave & 3;     // 0..3
    const int quad  = lane >> 4;    // 0..3 (k-chunk)
    const int l16   = lane & 15;
    const int soff  = (quad ^ ((l16 >> 1) & 3)) * 8;  // swizzled slot (shorts)
    const int rowA0 = waveM * 128 + l16;
    const int rowB0 = waveN * 64 + l16;

    // hoisted per-lane staging offsets (shorts): e = i*512+tid
    unsigned oo[2], dd[2];
    #pragma unroll
    for (int i = 0; i < 2; ++i) {
        int e = i * 512 + tid;
        int r = e >> 2;
        int c = (e & 3) ^ ((r >> 1) & 3);
        oo[i] = (unsigned)(r * K + c * 8);
        dd[i] = (unsigned)(e * 8);
    }

    // XCD-aware bijective swizzle (nwg = 1024, divisible by 8)
    const int nwg = gridDim.x;
    const int cpx = nwg >> 3;
    const int bid = blockIdx.x;
    const int wg  = (bid & 7) * cpx + (bid >> 3);
    const int tilesN = N >> 8;
    const int tm = wg / tilesN;
    const int tn = wg % tilesN;

    const unsigned short* gA = A  + (size_t)tm * GBM * K;
    const unsigned short* gB = Bt + (size_t)tn * GBN * K;

    const int NT = K >> 5;          // K-tiles of 32 (= 64 here, mult of 4)

    floatx4 acc[8][4] = {};
    short8 xa0[4], xa1[4], xb[4];   // set X (even tiles)
    short8 ya0[4], ya1[4], yb[4];   // set Y (odd tiles)

#define STAGE(ts, bu)                                                        \
    do {                                                                     \
        unsigned kb = (unsigned)(ts) * GBK;                                  \
        gload16(gA + (oo[0] + kb), &lds[bu][0]    + dd[0]);                  \
        gload16(gA + (oo[1] + kb), &lds[bu][0]    + dd[1]);                  \
        gload16(gB + (oo[0] + kb), &lds[bu][8192] + dd[0]);                  \
        gload16(gB + (oo[1] + kb), &lds[bu][8192] + dd[1]);                  \
    } while (0)

#define READF(bu, A0, A1, BB)                                                \
    do {                                                                     \
        const unsigned short* bA = &lds[bu][0]    + rowA0 * 32 + soff;       \
        const unsigned short* bB = &lds[bu][8192] + rowB0 * 32 + soff;       \
        _Pragma("unroll")                                                    \
        for (int i = 0; i < 4; ++i) A0[i] = *(const short8*)(bA + i * 512);  \
        _Pragma("unroll")                                                    \
        for (int j = 0; j < 4; ++j) BB[j] = *(const short8*)(bB + j * 512);  \
        _Pragma("unroll")                                                    \
        for (int i = 0; i < 4; ++i) A1[i] = *(const short8*)(bA + 2048 + i * 512); \
    } while (0)

#define MFMAT(A0, A1, BB)                                                    \
    do {                                                                     \
        __builtin_amdgcn_s_setprio(1);                                       \
        _Pragma("unroll")                                                    \
        for (int i = 0; i < 4; ++i)                                          \
            _Pragma("unroll")                                                \
            for (int j = 0; j < 4; ++j)                                      \
                acc[i][j] = __builtin_amdgcn_mfma_f32_16x16x32_bf16(         \
                    A0[i], BB[j], acc[i][j], 0, 0, 0);                       \
        _Pragma("unroll")                                                    \
        for (int i = 0; i < 4; ++i)                                          \
            _Pragma("unroll")                                                \
            for (int j = 0; j < 4; ++j)                                      \
                acc[4 + i][j] = __builtin_amdgcn_mfma_f32_16x16x32_bf16(     \
                    A1[i], BB[j], acc[4 + i][j], 0, 0, 0);                   \
        __builtin_amdgcn_s_setprio(0);                                       \
    } while (0)

    // prologue: stage tiles 0,1; retire tile 0 (4 loads stay in flight)
    STAGE(0, 0);
    STAGE(1, 1);
    asm volatile("s_waitcnt vmcnt(4)" ::: "memory");
    __builtin_amdgcn_s_barrier();

    for (int t = 0; t < NT; t += 4) {
        {   // u=0: reads tile t -> X, MFMA tile t-1 on Y
            int ts = t + 2; if (ts > NT - 1) ts = NT - 1;
            STAGE(ts, 2);
            READF(0, xa0, xa1, xb);
            asm volatile("s_waitcnt lgkmcnt(12)" ::: "memory");
            __builtin_amdgcn_sched_barrier(0);
            if (t > 0) MFMAT(ya0, ya1, yb);
            asm volatile("s_waitcnt vmcnt(4)" ::: "memory");
            __builtin_amdgcn_s_barrier();
        }
        {   // u=1: reads tile t+1 -> Y, MFMA tile t on X
            int ts = t + 3; if (ts > NT - 1) ts = NT - 1;
            STAGE(ts, 3);
            READF(1, ya0, ya1, yb);
            asm volatile("s_waitcnt lgkmcnt(12)" ::: "memory");
            __builtin_amdgcn_sched_barrier(0);
            MFMAT(xa0, xa1, xb);
            asm volatile("s_waitcnt vmcnt(4)" ::: "memory");
            __builtin_amdgcn_s_barrier();
        }
        {   // u=2: reads tile t+2 -> X, MFMA tile t+1 on Y
            int ts = t + 4; if (ts > NT - 1) ts = NT - 1;
            STAGE(ts, 0);
            READF(2, xa0, xa1, xb);
            asm volatile("s_waitcnt lgkmcnt(12)" ::: "memory");
            __builtin_amdgcn_sched_barrier(0);
            MFMAT(ya0, ya1, yb);
            asm volatile("s_waitcnt vmcnt(4)" ::: "memory");
            __builtin_amdgcn_s_barrier();
        }
        {   // u=3: reads tile t+3 -> Y, MFMA tile t+2 on X
            int ts = t + 5; if (ts > NT - 1) ts = NT - 1;
            STAGE(ts, 1);
            READF(3, ya0, ya1, yb);
            asm volatile("s_waitcnt lgkmcnt(12)" ::: "memory");
            __builtin_amdgcn_sched_barrier(0);
            MFMAT(xa0, xa1, xb);
            asm volatile("s_waitcnt vmcnt(4)" ::: "memory");
            __builtin_amdgcn_s_barrier();
        }
    }
    // epilogue: MFMA tile NT-1 (odd -> Y); its reads complete first
    asm volatile("s_waitcnt lgkmcnt(0)" ::: "memory");
    MFMAT(ya0, ya1, yb);

#undef STAGE
#undef READF
#undef MFMAT

    // epilogue: C/D layout col = lane&15 (N from B), row = quad*4 + reg (M)
    const size_t bm = (size_t)tm * GBM;
    const size_t bn = (size_t)tn * GBN;
    #pragma unroll
    for (int mi = 0; mi < 8; ++mi) {
        #pragma unroll
        for (int ni = 0; ni < 4; ++ni) {
            size_t col = bn + (size_t)waveN * 64 + ni * 16 + l16;
            #pragma unroll
            for (int r = 0; r < 4; ++r) {
                size_t row = bm + (size_t)waveM * 128 + mi * 16 + quad * 4 + r;
                C[row * N + col] = acc[mi][ni][r];
            }
        }
    }
}

// ---------------------------------------------------------------------------
extern "C" void kernel_launch(void* const* d_in, const int* in_sizes, int n_in,
                              void* d_out, int out_size, void* d_ws, size_t ws_size,
                              hipStream_t stream) {
    const float* x      = (const float*)d_in[0];
    const float* scale  = (const float*)d_in[1];
    const float* lnbias = (const float*)d_in[2];
    const float* W      = (const float*)d_in[3];

    const int H = in_sizes[1];                 // 2048
    const int M = in_sizes[0] / H;             // S*B = 8192
    const int F = in_sizes[3] / H;             // 8192

    float* z = (float*)d_out;                  // [M][F]
    float* y = z + (size_t)M * F;              // [M][H]

    unsigned short* Abf = (unsigned short*)d_ws;            // [M][H] bf16
    unsigned short* Btb = Abf + (size_t)M * H;              // [F][H] bf16

    ln_kernel<<<M, 256, 0, stream>>>(x, scale, lnbias, y, Abf, H);
    transpose_cast_kernel<<<dim3(F / 64, H / 64), 256, 0, stream>>>(W, Btb, H, F);
    gemm_bf16_8w<<<dim3((M / GBM) * (F / GBN)), 512, 0, stream>>>(Abf, Btb, z, M, F, H);
}